// Round 1
// baseline (151.395 us; speedup 1.0000x reference)
//
#include <hip/hip_runtime.h>
#include <math.h>

#define NB 32     // batch
#define NS 1024   // seq len
#define NT 64     // turns
#define ENC 768   // encoder dim

// K1: e[b,t] = dot(encoder[b, ids[b,t], 0:768], fc_w[0, 256:1024])
// One 64-lane wave per (b,t); 4 waves per 256-thread block.
// Each lane reads 3x float4 (12 floats), coalesced 1 KiB/instr per wave.
__global__ void compute_e_kernel(const float* __restrict__ enc,
                                 const float* __restrict__ fc_w,
                                 const int* __restrict__ ids,
                                 float* __restrict__ e_out) {
    const int wave = threadIdx.x >> 6;        // 0..3
    const int lane = threadIdx.x & 63;
    const int bt = blockIdx.x * 4 + wave;     // 0..2047
    const int b = bt >> 6;
    const int idx = ids[bt];                  // ids is [B][T] row-major, flat index = bt
    const float* row = enc + ((size_t)b * NS + (size_t)idx) * ENC;
    const float* we  = fc_w + 256;            // w_e = fc_w[0, 256:1024]

    float sum = 0.f;
#pragma unroll
    for (int c = 0; c < 3; ++c) {
        const int off = (c * 64 + lane) * 4;
        const float4 x = *(const float4*)(row + off);
        const float4 w = *(const float4*)(we + off);
        sum += x.x * w.x + x.y * w.y + x.z * w.z + x.w * w.w;
    }
#pragma unroll
    for (int s = 32; s > 0; s >>= 1) sum += __shfl_xor(sum, s, 64);
    if (lane == 0) e_out[bt] = sum;
}

// K2: per-batch suffix logsumexp scan.
//   loss[b,i] = logsumexp_{j=i+1..L-1}(e[b,j]) - e[b,i+1],  i in [0, L-2]
//   out = sum(loss) / sum(L_b - 1)
// One lane per batch (32 active of 64), then wave reduce.
__global__ void loss_kernel(const float* __restrict__ e,
                            const int* __restrict__ turn_len,
                            float* __restrict__ out) {
    const int lane = threadIdx.x;             // 64 threads, 1 block
    float loss = 0.f;
    float cnt = 0.f;
    if (lane < NB) {
        const int L = turn_len[lane];
        const float* eb = e + lane * NT;
        float s = -INFINITY;                  // suffix logsumexp over (i, L)
        for (int i = L - 2; i >= 0; --i) {
            const float x = eb[i + 1];
            const float m = fmaxf(x, s);
            s = m + logf(expf(x - m) + expf(s - m));  // expf(-inf)=0 handles first iter
            loss += s - x;
        }
        cnt = (float)(L - 1);
    }
#pragma unroll
    for (int s = 32; s > 0; s >>= 1) {
        loss += __shfl_xor(loss, s, 64);
        cnt  += __shfl_xor(cnt,  s, 64);
    }
    if (lane == 0) out[0] = loss / cnt;
}

extern "C" void kernel_launch(void* const* d_in, const int* in_sizes, int n_in,
                              void* d_out, int out_size, void* d_ws, size_t ws_size,
                              hipStream_t stream) {
    // Inputs (setup_inputs order):
    // 0 encoder_output (B,S,ENC) f32 | 1 W_ih | 2 W_hh | 3 b_ih | 4 b_hh
    // 5 fc_w (1,1024) f32 | 6 fc_b | 7 his_turn_end_ids (B,T) i32 | 8 turn_lengths (B,) i32
    // The LSTM path (1,2,3,4, fc_w[:256], fc_b) cancels out of the loss algebraically.
    const float* enc  = (const float*)d_in[0];
    const float* fc_w = (const float*)d_in[5];
    const int*   ids  = (const int*)d_in[7];
    const int*   tlen = (const int*)d_in[8];
    float* e = (float*)d_ws;                  // B*T floats = 8 KiB scratch

    compute_e_kernel<<<(NB * NT) / 4, 256, 0, stream>>>(enc, fc_w, ids, e);
    loss_kernel<<<1, 64, 0, stream>>>(e, tlen, (float*)d_out);
}